// Round 5
// baseline (299.675 us; speedup 1.0000x reference)
//
#include <hip/hip_runtime.h>
#include <hip/hip_bf16.h>

// QKVAttention: L2-distance attention. B=8, T=4096, C=192, fp32 in/out.
// out[b,t,:] = sum_s exp(-||q_t-k_s||*192^-0.5) v_s / sum_s exp(...)
// exp arg bounded in [-3,0] -> no online softmax needed.
//
// R5: R4 was LDS-read-BW bound (each wave re-reads shared K/V; plus P LDS
// round-trip). Changes:
//  - MT=2: 32 q-rows/wave -> K/V LDS reads serve 2x compute.
//  - S^T trick: compute S^T = (A=K)x(B=Q); its C-layout (lane(q,L) ->
//    P[t=L][s=4q+r]) IS the A-layout of mfma_16x16x16 (A[m=L][k=4q+j]) ->
//    P feeds PV straight from registers. P scratch LDS deleted.
//  - Channel-split: each block computes 96 of 192 output channels (h=0/1);
//    QK^T+softmax duplicated (VALU not binding), outputs disjoint -> no
//    combine kernel. grid 512 = 32 qt x 2 h x 8 b, LDS 36KB, 2-3 blocks/CU.
//  - fp16 everywhere (better mantissa than bf16; P in [0.05,1], V ~N(0,1)).

#define BB 8
#define TT 4096
#define CD 192

typedef __attribute__((ext_vector_type(8))) _Float16 half8;
typedef __attribute__((ext_vector_type(4))) _Float16 half4;
typedef __attribute__((ext_vector_type(8))) short short8;   // raw f16 bits
typedef __attribute__((ext_vector_type(4))) float float4v;
typedef __attribute__((ext_vector_type(2))) unsigned int uint2v;

// dist = sqrt(d2_raw * (log2e)^2/192); p = 2^-dist. Fold into prescaled sumsq.
constexpr float A2C = (float)(2.0813689810056077 / 192.0);
constexpr float M2A2C = -2.0f * A2C;

static __device__ __forceinline__ unsigned short f2h(float f) {
  return __builtin_bit_cast(unsigned short, (_Float16)f);   // v_cvt_f16_f32 RNE
}
static __device__ __forceinline__ float h2f(unsigned short u) {
  return (float)__builtin_bit_cast(_Float16, u);
}

// ---------------- fused prepass: qkv -> qsw/ksw/vsw f16 fragments + q2/k2 ---
// block = (b, sc): 32 tokens x 576 ch. Coalesced float4 read -> f16 LDS tile,
// then emit MFMA-fragment units + A2C-prescaled rounded row sumsq.
__global__ __launch_bounds__(256) void prep(
    const float* __restrict__ qkv, short8* __restrict__ qsw,
    short8* __restrict__ ksw, short8* __restrict__ vsw,
    float* __restrict__ q2A, float* __restrict__ k2A) {
  __shared__ unsigned short tile[32 * 584];   // row stride 584 (16B-mult)
  const int t = threadIdx.x;
  const int b = blockIdx.x >> 7;
  const int sc = blockIdx.x & 127;
  const float* src = qkv + ((size_t)(b * TT + sc * 32)) * (3 * CD);
#pragma unroll
  for (int j = 0; j < 18; ++j) {              // 4608 float4s / 256 thr
    int f = j * 256 + t;
    int row = f / 144, c4 = (f % 144) * 4;
    float4v x = *(const float4v*)(src + (size_t)row * 576 + c4);
    unsigned r0 = (unsigned)f2h(x[0]) | ((unsigned)f2h(x[1]) << 16);
    unsigned r1 = (unsigned)f2h(x[2]) | ((unsigned)f2h(x[3]) << 16);
    *(uint2v*)&tile[row * 584 + c4] = (uint2v){r0, r1};
  }
  __syncthreads();

  const int lane = t & 63, w = t >> 6;
  const int L = lane & 15, q = lane >> 4;
  // waves 0,1 -> q (s16o = w), waves 2,3 -> k
  const int which = w >> 1;
  const int s16o = w & 1;
  const int row = s16o * 16 + L;
  short8* dst = which ? ksw : qsw;
  const size_t ubase = ((size_t)(b * 256 + sc * 2 + s16o)) * 6;
  float ss = 0.f;
#pragma unroll
  for (int ch = 0; ch < 6; ++ch) {
    short8 fr = *(const short8*)&tile[row * 584 + which * CD + ch * 32 + q * 8];
#pragma unroll
    for (int j = 0; j < 8; ++j) {
      float f = h2f((unsigned short)fr[j]);
      ss += f * f;
    }
    dst[(ubase + ch) * 64 + lane] = fr;
  }
  ss += __shfl_xor(ss, 16);
  ss += __shfl_xor(ss, 32);                   // sum over 4 quads (192 ch)
  if (lane < 16)
    (which ? k2A : q2A)[b * TT + sc * 32 + s16o * 16 + lane] = ss * A2C;

  // V: B-operand units for mfma_16x16x16: lane(q,L) holds
  // lo: V[sc*32 + 4q+j][ct*16+L] j=0..3, hi: V[sc*32+16+4q+j][ct*16+L].
#pragma unroll
  for (int i = 0; i < 3; ++i) {
    int ct = w * 3 + i;
    short8 fr;
#pragma unroll
    for (int j = 0; j < 4; ++j) {
      fr[j]     = (short)tile[(4 * q + j) * 584 + 2 * CD + ct * 16 + L];
      fr[j + 4] = (short)tile[(16 + 4 * q + j) * 584 + 2 * CD + ct * 16 + L];
    }
    vsw[((size_t)(b * 12 + ct) * 128 + sc) * 64 + lane] = fr;
  }
}

// ---------------- main fused attention --------------------------------------
// grid 512: blockIdx = qt*16 + h*8 + b. block 256 = 4 waves x 32 q-rows
// (MT=2). 128 s-iters of 32. Block computes channels [h*96, h*96+96).
// LDS 36864B: K dbuf 2x12KB + V dbuf 2x6KB. 2-3 blocks/CU.
__global__ __launch_bounds__(256, 2) void attn3(
    const short8* __restrict__ qsw, const short8* __restrict__ ksw,
    const short8* __restrict__ vsw, const float* __restrict__ q2A,
    const float* __restrict__ k2A, float* __restrict__ out) {
  __shared__ __align__(16) unsigned char s_lds[36864];

  const int tid = threadIdx.x;
  const int w = tid >> 6;
  const int lane = tid & 63;
  const int L = lane & 15;
  const int q = lane >> 4;
  const int b = blockIdx.x & 7;          // batch -> XCD
  const int h = (blockIdx.x >> 3) & 1;   // channel half
  const int qt = blockIdx.x >> 4;        // 0..31
  const int q0 = qt * 128 + w * 32;      // wave's first q-row (32 rows, MT=2)
  const size_t bT = (size_t)b * TT;

  // stage s-tile 'it' (32 tokens: 12 K units + 6 V units) into buffer buf
  auto stage = [&](int it, int buf) {
#pragma unroll
    for (int j = 0; j < 5; ++j) {
      int u = w + 4 * j;                 // wave-uniform unit id 0..17
      if (u < 12) {
        int so = u / 6, ch = u % 6;
        const char* ga = (const char*)ksw +
            (((size_t)(b * 256 + it * 2 + so) * 6 + ch) * 64 + lane) * 16;
        char* la = (char*)s_lds + buf * 12288 + u * 1024;
        __builtin_amdgcn_global_load_lds(
            (const __attribute__((address_space(1))) void*)ga,
            (__attribute__((address_space(3))) void*)la, 16, 0, 0);
      } else if (u < 18) {
        int j2 = u - 12;
        const char* ga = (const char*)vsw +
            (((size_t)(b * 12 + h * 6 + j2) * 128 + it) * 64 + lane) * 16;
        char* la = (char*)s_lds + 24576 + buf * 6144 + j2 * 1024;
        __builtin_amdgcn_global_load_lds(
            (const __attribute__((address_space(1))) void*)ga,
            (__attribute__((address_space(3))) void*)la, 16, 0, 0);
      }
    }
  };

  // Q fragments (B-operand of S^T mfma): unit ((b*256 + s16)*6 + ch)
  half8 qf[2][6];
#pragma unroll
  for (int mt = 0; mt < 2; ++mt)
#pragma unroll
    for (int ch = 0; ch < 6; ++ch)
      qf[mt][ch] = __builtin_bit_cast(
          half8, qsw[((size_t)(b * 256 + (q0 >> 4) + mt) * 6 + ch) * 64 + lane]);

  float q2l[2];
  q2l[0] = q2A[bT + q0 + L];
  q2l[1] = q2A[bT + q0 + 16 + L];

  float4v oacc[2][6];
#pragma unroll
  for (int mt = 0; mt < 2; ++mt)
#pragma unroll
    for (int ct = 0; ct < 6; ++ct) oacc[mt][ct] = (float4v){0.f, 0.f, 0.f, 0.f};
  float lsum[2] = {0.f, 0.f};

  stage(0, 0);
  __syncthreads();

#pragma unroll 1
  for (int it = 0; it < 128; ++it) {
    const int cur = it & 1;
    if (it + 1 < 128) stage(it + 1, cur ^ 1);
    const int s0 = it * 32;

    // k2 for this lane's s positions: s = s0 + n*16 + 4q + r (broadcast load)
    float4v k2l[2];
    k2l[0] = *(const float4v*)(k2A + bT + s0 + 4 * q);
    k2l[1] = *(const float4v*)(k2A + bT + s0 + 16 + 4 * q);

    // ---- S^T = K.Q^T : lane(q,L) -> P-chunk[n][t=L][s=4q+r] ----
    float4v sacc[2][2];
#pragma unroll
    for (int mt = 0; mt < 2; ++mt)
#pragma unroll
      for (int n = 0; n < 2; ++n) sacc[mt][n] = (float4v){0.f, 0.f, 0.f, 0.f};
#pragma unroll
    for (int ch = 0; ch < 6; ++ch) {
      half8 kf0 = *(const half8*)(s_lds + cur * 12288 + ch * 1024 + lane * 16);
      half8 kf1 = *(const half8*)(s_lds + cur * 12288 + (6 + ch) * 1024 + lane * 16);
      sacc[0][0] = __builtin_amdgcn_mfma_f32_16x16x32_f16(kf0, qf[0][ch], sacc[0][0], 0, 0, 0);
      sacc[0][1] = __builtin_amdgcn_mfma_f32_16x16x32_f16(kf1, qf[0][ch], sacc[0][1], 0, 0, 0);
      sacc[1][0] = __builtin_amdgcn_mfma_f32_16x16x32_f16(kf0, qf[1][ch], sacc[1][0], 0, 0, 0);
      sacc[1][1] = __builtin_amdgcn_mfma_f32_16x16x32_f16(kf1, qf[1][ch], sacc[1][1], 0, 0, 0);
    }

    // ---- P = exp(-dist): stays in registers as PV A-fragments (K=16) ----
    half4 paf[2][2];
#pragma unroll
    for (int mt = 0; mt < 2; ++mt)
#pragma unroll
      for (int n = 0; n < 2; ++n) {
        float4v pv;
#pragma unroll
        for (int r = 0; r < 4; ++r) {
          float tt = fmaf(sacc[mt][n][r], M2A2C, q2l[mt] + k2l[n][r]);
          float p = __builtin_amdgcn_exp2f(-__builtin_amdgcn_sqrtf(fmaxf(tt, 0.f)));
          lsum[mt] += p;
          pv[r] = p;
        }
        paf[mt][n] = (half4){(_Float16)pv[0], (_Float16)pv[1],
                             (_Float16)pv[2], (_Float16)pv[3]};
      }

    // ---- O += P.V via mfma_16x16x16 (V B-fragments from LDS) ----
#pragma unroll
    for (int ct = 0; ct < 6; ++ct) {
      half8 vv = *(const half8*)(s_lds + 24576 + cur * 6144 + ct * 1024 + lane * 16);
      half4 vlo = __builtin_shufflevector(vv, vv, 0, 1, 2, 3);
      half4 vhi = __builtin_shufflevector(vv, vv, 4, 5, 6, 7);
      oacc[0][ct] = __builtin_amdgcn_mfma_f32_16x16x16f16(paf[0][0], vlo, oacc[0][ct], 0, 0, 0);
      oacc[0][ct] = __builtin_amdgcn_mfma_f32_16x16x16f16(paf[0][1], vhi, oacc[0][ct], 0, 0, 0);
      oacc[1][ct] = __builtin_amdgcn_mfma_f32_16x16x16f16(paf[1][0], vlo, oacc[1][ct], 0, 0, 0);
      oacc[1][ct] = __builtin_amdgcn_mfma_f32_16x16x16f16(paf[1][1], vhi, oacc[1][ct], 0, 0, 0);
    }

    __syncthreads();   // release buf[cur] / tile it+1 ready
  }

  // ---- epilogue: lsum[t=L] -> broadcast to rows t=4q+r, normalize, write ---
#pragma unroll
  for (int mt = 0; mt < 2; ++mt) {
    float ls = lsum[mt];
    ls += __shfl_xor(ls, 16);
    ls += __shfl_xor(ls, 32);          // full row-sum for t = L
#pragma unroll
    for (int r = 0; r < 4; ++r) {
      float linv = 1.f / __shfl(ls, 4 * q + r);   // lsum for t = 4q+r
#pragma unroll
      for (int ct = 0; ct < 6; ++ct)
        out[(bT + q0 + mt * 16 + 4 * q + r) * CD + (h * 6 + ct) * 16 + L] =
            oacc[mt][ct][r] * linv;
    }
  }
}

extern "C" void kernel_launch(void* const* d_in, const int* in_sizes, int n_in,
                              void* d_out, int out_size, void* d_ws, size_t ws_size,
                              hipStream_t stream) {
  (void)in_sizes; (void)n_in; (void)out_size; (void)ws_size;
  const float* qkv = (const float*)d_in[0];
  float* out = (float*)d_out;

  short8* qsw = (short8*)d_ws;                       // 8*256*6 units
  short8* ksw = qsw + (size_t)BB * 256 * 6 * 64;
  short8* vsw = ksw + (size_t)BB * 256 * 6 * 64;     // 8*12*128 units
  float* q2A = (float*)(vsw + (size_t)BB * 12 * 128 * 64);
  float* k2A = q2A + (size_t)BB * TT;

  prep<<<BB * 128, 256, 0, stream>>>(qkv, qsw, ksw, vsw, q2A, k2A);
  attn3<<<BB * 64, 256, 0, stream>>>(qsw, ksw, vsw, q2A, k2A, out);
}

// Round 6
// 246.928 us; speedup vs baseline: 1.2136x; 1.2136x over previous
//
#include <hip/hip_runtime.h>
#include <hip/hip_bf16.h>

// QKVAttention: L2-distance attention. B=8, T=4096, C=192, fp32 in/out.
// out[b,t,:] = sum_s exp(-||q_t-k_s||*192^-0.5) v_s / sum_s exp(...)
// exp arg bounded in [-3,0] -> no online softmax needed.
//
// R6: R5's channel split duplicated QK^T+softmax (MFMA 103->155 GF) -> both
// issue pipes saturated with redundant work. Now: MT=2 (32 q-rows/wave),
// FULL 192 channels (no duplication), concurrency restored via split-K over
// s (sk=0/1 x 2048 tokens) -> grid 512, 2 blocks/CU, independent barriers.
// Partials: sk0 -> d_out, sk1 -> ws (fp32, L3-resident); tiny combine pass.
// Keeps R5's verified S^T register trick (P never leaves registers) and f16.
// LDS economy: 120KB/block-iter for 128 q-rows (R4: 137KB for 64 rows).

#define BB 8
#define TT 4096
#define CD 192

typedef __attribute__((ext_vector_type(8))) _Float16 half8;
typedef __attribute__((ext_vector_type(4))) _Float16 half4;
typedef __attribute__((ext_vector_type(8))) short short8;   // raw f16 bits
typedef __attribute__((ext_vector_type(4))) float float4v;
typedef __attribute__((ext_vector_type(2))) unsigned int uint2v;

// dist = sqrt(d2_raw * (log2e)^2/192); p = 2^-dist. Fold into prescaled sumsq.
constexpr float A2C = (float)(2.0813689810056077 / 192.0);
constexpr float M2A2C = -2.0f * A2C;

static __device__ __forceinline__ unsigned short f2h(float f) {
  return __builtin_bit_cast(unsigned short, (_Float16)f);   // v_cvt_f16_f32 RNE
}
static __device__ __forceinline__ float h2f(unsigned short u) {
  return (float)__builtin_bit_cast(_Float16, u);
}

// ---------------- fused prepass: qkv -> qsw/ksw/vsw f16 fragments + q2/k2 ---
// block = (b, sc): 32 tokens x 576 ch. Coalesced float4 read -> f16 LDS tile,
// then emit MFMA-fragment units + A2C-prescaled rounded row sumsq.
__global__ __launch_bounds__(256) void prep(
    const float* __restrict__ qkv, short8* __restrict__ qsw,
    short8* __restrict__ ksw, short8* __restrict__ vsw,
    float* __restrict__ q2A, float* __restrict__ k2A) {
  __shared__ unsigned short tile[32 * 584];   // row stride 584 (16B-mult)
  const int t = threadIdx.x;
  const int b = blockIdx.x >> 7;
  const int sc = blockIdx.x & 127;
  const float* src = qkv + ((size_t)(b * TT + sc * 32)) * (3 * CD);
#pragma unroll
  for (int j = 0; j < 18; ++j) {              // 4608 float4s / 256 thr
    int f = j * 256 + t;
    int row = f / 144, c4 = (f % 144) * 4;
    float4v x = *(const float4v*)(src + (size_t)row * 576 + c4);
    unsigned r0 = (unsigned)f2h(x[0]) | ((unsigned)f2h(x[1]) << 16);
    unsigned r1 = (unsigned)f2h(x[2]) | ((unsigned)f2h(x[3]) << 16);
    *(uint2v*)&tile[row * 584 + c4] = (uint2v){r0, r1};
  }
  __syncthreads();

  const int lane = t & 63, w = t >> 6;
  const int L = lane & 15, q = lane >> 4;
  // waves 0,1 -> q (s16o = w), waves 2,3 -> k
  const int which = w >> 1;
  const int s16o = w & 1;
  const int row = s16o * 16 + L;
  short8* dst = which ? ksw : qsw;
  const size_t ubase = ((size_t)(b * 256 + sc * 2 + s16o)) * 6;
  float ss = 0.f;
#pragma unroll
  for (int ch = 0; ch < 6; ++ch) {
    short8 fr = *(const short8*)&tile[row * 584 + which * CD + ch * 32 + q * 8];
#pragma unroll
    for (int j = 0; j < 8; ++j) {
      float f = h2f((unsigned short)fr[j]);
      ss += f * f;
    }
    dst[(ubase + ch) * 64 + lane] = fr;
  }
  ss += __shfl_xor(ss, 16);
  ss += __shfl_xor(ss, 32);                   // sum over 4 quads (192 ch)
  if (lane < 16)
    (which ? k2A : q2A)[b * TT + sc * 32 + s16o * 16 + lane] = ss * A2C;

  // V: B-operand units for mfma_16x16x16: lane(q,L) holds
  // lo: V[sc*32 + 4q+j][ct*16+L] j=0..3, hi: V[sc*32+16+4q+j][ct*16+L].
#pragma unroll
  for (int i = 0; i < 3; ++i) {
    int ct = w * 3 + i;
    short8 fr;
#pragma unroll
    for (int j = 0; j < 4; ++j) {
      fr[j]     = (short)tile[(4 * q + j) * 584 + 2 * CD + ct * 16 + L];
      fr[j + 4] = (short)tile[(16 + 4 * q + j) * 584 + 2 * CD + ct * 16 + L];
    }
    vsw[((size_t)(b * 12 + ct) * 128 + sc) * 64 + lane] = fr;
  }
}

// ---------------- main fused attention (split-K partials) -------------------
// grid 512: blockIdx = qt*16 + sk*8 + b. block 256 = 4 waves x 32 q-rows
// (MT=2), FULL 192 channels. Block covers s in [sk*2048, +2048): 64 iters.
// LDS 49152B: K dbuf 2x12KB + V dbuf 2x12KB. 2 blocks/CU, indep barriers.
__global__ __launch_bounds__(256, 2) void attn4(
    const short8* __restrict__ qsw, const short8* __restrict__ ksw,
    const short8* __restrict__ vsw, const float* __restrict__ q2A,
    const float* __restrict__ k2A, float* __restrict__ out,
    float* __restrict__ opart1, float* __restrict__ lpart) {
  __shared__ __align__(16) unsigned char s_lds[49152];

  const int tid = threadIdx.x;
  const int w = tid >> 6;
  const int lane = tid & 63;
  const int L = lane & 15;
  const int q = lane >> 4;
  const int b = blockIdx.x & 7;          // batch -> XCD
  const int sk = (blockIdx.x >> 3) & 1;  // s-half
  const int qt = blockIdx.x >> 4;        // 0..31
  const int q0 = qt * 128 + w * 32;      // wave's first q-row (32 rows, MT=2)
  const size_t bT = (size_t)b * TT;

  // stage s-tile itg (32 tokens: 12 K units + 12 V units); 6 units per wave
  auto stage = [&](int itg, int buf) {
#pragma unroll
    for (int j = 0; j < 6; ++j) {
      int u = w * 6 + j;                 // 0..23, wave-uniform
      if (u < 12) {
        int so = u / 6, ch = u % 6;
        const char* ga = (const char*)ksw +
            (((size_t)(b * 256 + itg * 2 + so) * 6 + ch) * 64 + lane) * 16;
        char* la = (char*)s_lds + buf * 12288 + u * 1024;
        __builtin_amdgcn_global_load_lds(
            (const __attribute__((address_space(1))) void*)ga,
            (__attribute__((address_space(3))) void*)la, 16, 0, 0);
      } else {
        int ct = u - 12;
        const char* ga = (const char*)vsw +
            (((size_t)(b * 12 + ct) * 128 + itg) * 64 + lane) * 16;
        char* la = (char*)s_lds + 24576 + buf * 12288 + ct * 1024;
        __builtin_amdgcn_global_load_lds(
            (const __attribute__((address_space(1))) void*)ga,
            (__attribute__((address_space(3))) void*)la, 16, 0, 0);
      }
    }
  };

  // Q fragments (B-operand of S^T mfma): unit ((b*256 + s16)*6 + ch)
  half8 qf[2][6];
#pragma unroll
  for (int mt = 0; mt < 2; ++mt)
#pragma unroll
    for (int ch = 0; ch < 6; ++ch)
      qf[mt][ch] = __builtin_bit_cast(
          half8, qsw[((size_t)(b * 256 + (q0 >> 4) + mt) * 6 + ch) * 64 + lane]);

  float q2l[2];
  q2l[0] = q2A[bT + q0 + L];
  q2l[1] = q2A[bT + q0 + 16 + L];

  float4v oacc[2][12];
#pragma unroll
  for (int mt = 0; mt < 2; ++mt)
#pragma unroll
    for (int ct = 0; ct < 12; ++ct) oacc[mt][ct] = (float4v){0.f, 0.f, 0.f, 0.f};
  float lsum[2] = {0.f, 0.f};

  stage(sk * 64, 0);
  __syncthreads();

#pragma unroll 1
  for (int it = 0; it < 64; ++it) {
    const int cur = it & 1;
    if (it + 1 < 64) stage(sk * 64 + it + 1, cur ^ 1);
    const int s0 = sk * 2048 + it * 32;

    // k2 for this lane's s positions: s = s0 + n*16 + 4q + r (broadcast load)
    float4v k2l[2];
    k2l[0] = *(const float4v*)(k2A + bT + s0 + 4 * q);
    k2l[1] = *(const float4v*)(k2A + bT + s0 + 16 + 4 * q);

    // ---- S^T = K.Q^T : lane(q,L) -> P-chunk[n][t=L][s=4q+r] ----
    float4v sacc[2][2];
#pragma unroll
    for (int mt = 0; mt < 2; ++mt)
#pragma unroll
      for (int n = 0; n < 2; ++n) sacc[mt][n] = (float4v){0.f, 0.f, 0.f, 0.f};
#pragma unroll
    for (int ch = 0; ch < 6; ++ch) {
      half8 kf0 = *(const half8*)(s_lds + cur * 12288 + ch * 1024 + lane * 16);
      half8 kf1 = *(const half8*)(s_lds + cur * 12288 + (6 + ch) * 1024 + lane * 16);
      sacc[0][0] = __builtin_amdgcn_mfma_f32_16x16x32_f16(kf0, qf[0][ch], sacc[0][0], 0, 0, 0);
      sacc[0][1] = __builtin_amdgcn_mfma_f32_16x16x32_f16(kf1, qf[0][ch], sacc[0][1], 0, 0, 0);
      sacc[1][0] = __builtin_amdgcn_mfma_f32_16x16x32_f16(kf0, qf[1][ch], sacc[1][0], 0, 0, 0);
      sacc[1][1] = __builtin_amdgcn_mfma_f32_16x16x32_f16(kf1, qf[1][ch], sacc[1][1], 0, 0, 0);
    }

    // ---- P = exp(-dist): stays in registers as PV A-fragments (K=16) ----
    half4 paf[2][2];
#pragma unroll
    for (int mt = 0; mt < 2; ++mt)
#pragma unroll
      for (int n = 0; n < 2; ++n) {
        float4v pv;
#pragma unroll
        for (int r = 0; r < 4; ++r) {
          float tt = fmaf(sacc[mt][n][r], M2A2C, q2l[mt] + k2l[n][r]);
          // |neg d2| ~1e-3 max -> sqrt(|d2|) error negligible; fabs is free
          float p = __builtin_amdgcn_exp2f(-__builtin_amdgcn_sqrtf(__builtin_fabsf(tt)));
          lsum[mt] += p;
          pv[r] = p;
        }
        paf[mt][n] = (half4){(_Float16)pv[0], (_Float16)pv[1],
                             (_Float16)pv[2], (_Float16)pv[3]};
      }

    // ---- O += P.V via mfma_16x16x16 (V B-fragments from LDS) ----
#pragma unroll
    for (int ct = 0; ct < 12; ++ct) {
      half8 vv = *(const half8*)(s_lds + 24576 + cur * 12288 + ct * 1024 + lane * 16);
      half4 vlo = __builtin_shufflevector(vv, vv, 0, 1, 2, 3);
      half4 vhi = __builtin_shufflevector(vv, vv, 4, 5, 6, 7);
      oacc[0][ct] = __builtin_amdgcn_mfma_f32_16x16x16f16(paf[0][0], vlo, oacc[0][ct], 0, 0, 0);
      oacc[0][ct] = __builtin_amdgcn_mfma_f32_16x16x16f16(paf[0][1], vhi, oacc[0][ct], 0, 0, 0);
      oacc[1][ct] = __builtin_amdgcn_mfma_f32_16x16x16f16(paf[1][0], vlo, oacc[1][ct], 0, 0, 0);
      oacc[1][ct] = __builtin_amdgcn_mfma_f32_16x16x16f16(paf[1][1], vhi, oacc[1][ct], 0, 0, 0);
    }

    __syncthreads();   // release buf[cur] / tile it+1 ready
  }

  // ---- epilogue: write partials (sk0 -> out, sk1 -> opart1) + lsum ----
  float* odst = sk ? opart1 : out;
#pragma unroll
  for (int mt = 0; mt < 2; ++mt) {
    float ls = lsum[mt];
    ls += __shfl_xor(ls, 16);
    ls += __shfl_xor(ls, 32);          // partial row-sum for t = q0+mt*16+L
    if (lane < 16)
      lpart[(size_t)sk * (BB * TT) + bT + q0 + mt * 16 + L] = ls;
#pragma unroll
    for (int r = 0; r < 4; ++r)
#pragma unroll
      for (int ct = 0; ct < 12; ++ct)
        odst[(bT + q0 + mt * 16 + 4 * q + r) * CD + ct * 16 + L] =
            oacc[mt][ct][r];
  }
}

// ---------------- combine: out = (out + opart1) / (l0 + l1) -----------------
__global__ __launch_bounds__(256) void combine(
    float* __restrict__ out, const float* __restrict__ opart1,
    const float* __restrict__ lpart) {
  int idx = blockIdx.x * 256 + threadIdx.x;     // over 8*4096*48 float4 groups
  int row = idx / 48;                            // b*4096 + t
  float linv = 1.f / (lpart[row] + lpart[BB * TT + row]);
  float4v a = *(const float4v*)(out + (size_t)idx * 4);
  float4v c = *(const float4v*)(opart1 + (size_t)idx * 4);
  float4v r = (a + c) * linv;
  *(float4v*)(out + (size_t)idx * 4) = r;
}

extern "C" void kernel_launch(void* const* d_in, const int* in_sizes, int n_in,
                              void* d_out, int out_size, void* d_ws, size_t ws_size,
                              hipStream_t stream) {
  (void)in_sizes; (void)n_in; (void)out_size; (void)ws_size;
  const float* qkv = (const float*)d_in[0];
  float* out = (float*)d_out;

  short8* qsw = (short8*)d_ws;                       // 8*256*6 units
  short8* ksw = qsw + (size_t)BB * 256 * 6 * 64;
  short8* vsw = ksw + (size_t)BB * 256 * 6 * 64;     // 8*12*128 units
  float* q2A = (float*)(vsw + (size_t)BB * 12 * 128 * 64);
  float* k2A = q2A + (size_t)BB * TT;
  float* opart1 = k2A + (size_t)BB * TT;             // 25.2 MB sk=1 partial
  float* lpart = opart1 + (size_t)BB * TT * CD;      // 2*8*4096 fp32

  prep<<<BB * 128, 256, 0, stream>>>(qkv, qsw, ksw, vsw, q2A, k2A);
  attn4<<<BB * 64, 256, 0, stream>>>(qsw, ksw, vsw, q2A, k2A, out, opart1, lpart);
  combine<<<BB * TT * (CD / 4) / 256, 256, 0, stream>>>(out, opart1, lpart);
}